// Round 3
// baseline (59376.105 us; speedup 1.0000x reference)
//
#include <hip/hip_runtime.h>
#include <cstdint>
#include <cstddef>

#define DEVFN __device__ __forceinline__

static constexpr int B  = 32;
static constexpr int T1 = 1024;
static constexpr int F0 = 240;
static constexpr int H  = 512;
static constexpr int G3 = 3 * H;   // 1536

// ---- module-scope scratch (device .bss; avoids unknown ws_size) ----
__device__ float g_XPF[(size_t)B * T1 * G3];
__device__ float g_XPB[(size_t)B * T1 * G3];
__device__ float g_YF [(size_t)B * T1 * H];
__device__ float g_YB [(size_t)B * T1 * H];
__device__ float g_HFIN[2 * B * H];
__device__ int   g_MK1[B * T1];
__device__ int   g_MK2[B * (T1 / 2)];
__device__ int   g_MK3[B * (T1 / 4)];
__device__ int   g_MK4[B * (T1 / 8)];
// batched-recurrence state: [parity][dir][b][k]
__device__ float g_Hbuf[2][2][B][H];
// grid barriers: one per (layer, dir)
__device__ int   g_bar[8];

DEVFN float fsig(float x)  { return 1.0f / (1.0f + expf(-x)); }

// ---------------------------------------------------------------------------
__global__ void init_misc() {
    if (threadIdx.x < 8) g_bar[threadIdx.x] = 0;
}

// ---------------------------------------------------------------------------
// mask for layer 1: one wave per (b,t) row; any nonzero among 240 feats
// ---------------------------------------------------------------------------
__global__ __launch_bounds__(256) void mask1_kernel(const float* __restrict__ x,
                                                    int* __restrict__ mask) {
    int wave = blockIdx.x * 4 + (threadIdx.x >> 6);
    int lane = threadIdx.x & 63;
    if (wave >= B * T1) return;
    const float* row = x + (size_t)wave * F0;
    int nz = 0;
    for (int f = lane; f < F0; f += 64) nz |= (row[f] != 0.0f);
    nz = __any(nz);
    if (lane == 0) mask[wave] = nz ? 1 : 0;
}

__global__ __launch_bounds__(256) void mask_down(const int* __restrict__ mp,
                                                 int* __restrict__ m, int n, int Tn) {
    int i = blockIdx.x * 256 + threadIdx.x;
    if (i >= n) return;
    int b = i / Tn, t = i - b * Tn;
    m[i] = mp[b * 2 * Tn + 2 * t] | mp[b * 2 * Tn + 2 * t + 1];
}

// ---------------------------------------------------------------------------
// xproj GEMM (unchanged from R2): C[M][1536] = A[M][K] @ W[K][1536]
// ---------------------------------------------------------------------------
template <int PYR>
__global__ __launch_bounds__(256)
void gemm_xproj(const float* __restrict__ A,
                const float* __restrict__ YFp, const float* __restrict__ YBp,
                const float* __restrict__ W, float* __restrict__ C,
                int M, int K, int Tn) {
    __shared__ float At[16][128];
    __shared__ float Bs[16][128];
    int tid = threadIdx.x;
    int n0 = blockIdx.x * 128;
    int m0 = blockIdx.y * 128;
    int tm = tid & 15, tn = tid >> 4;
    float acc[8][8] = {};

    for (int k0 = 0; k0 < K; k0 += 16) {
#pragma unroll
        for (int it = 0; it < 2; ++it) {
            int i = tid + it * 256;
            int m = i >> 2, kg = (i & 3) * 4;
            int gm = m0 + m, gk = k0 + kg;
            float4 v;
            if (PYR == 0) {
                v = *(const float4*)(A + (size_t)gm * K + gk);
            } else {
                int b = gm / Tn, t = gm - b * Tn;
                int s = 2 * t + (gk >> 10);
                int g = gk & 1023;
                const float* src = (g < 512)
                    ? (YFp + ((size_t)(b * 2 * Tn + s) * 512 + g))
                    : (YBp + ((size_t)(b * 2 * Tn + s) * 512 + (g - 512)));
                v = *(const float4*)src;
            }
            At[kg + 0][m] = v.x; At[kg + 1][m] = v.y;
            At[kg + 2][m] = v.z; At[kg + 3][m] = v.w;
        }
#pragma unroll
        for (int it = 0; it < 2; ++it) {
            int i = tid + it * 256;
            int kk = i >> 5, n4 = (i & 31) * 4;
            *(float4*)&Bs[kk][n4] =
                *(const float4*)(W + (size_t)(k0 + kk) * G3 + n0 + n4);
        }
        __syncthreads();
#pragma unroll
        for (int kk = 0; kk < 16; ++kk) {
            float a[8], bb[8];
            *(float4*)&a[0]  = *(float4*)&At[kk][tm * 8];
            *(float4*)&a[4]  = *(float4*)&At[kk][tm * 8 + 4];
            *(float4*)&bb[0] = *(float4*)&Bs[kk][tn * 8];
            *(float4*)&bb[4] = *(float4*)&Bs[kk][tn * 8 + 4];
#pragma unroll
            for (int i = 0; i < 8; ++i)
#pragma unroll
                for (int j = 0; j < 8; ++j) acc[i][j] += a[i] * bb[j];
        }
        __syncthreads();
    }
#pragma unroll
    for (int i = 0; i < 8; ++i) {
        size_t row = (size_t)(m0 + tm * 8 + i) * G3 + n0 + tn * 8;
        *(float4*)(C + row)     = *(float4*)&acc[i][0];
        *(float4*)(C + row + 4) = *(float4*)&acc[i][4];
    }
}

// ---------------------------------------------------------------------------
// Batched GRU recurrence, persistent cooperative kernel.
// Grid = 256 WGs x 256 thr. dir = blk&1 (XCD-parity L2 locality),
// slice = blk>>1 owns u-cols [u0,u0+4) => gate cols {u0..}+{512+u0..}+{1024+u0..}.
// Weight slice (12 cols x 512) persistent in LDS across all T steps.
// Per step: stage full h (32x512) from global double-buffer, 384 dot-products
// (192 thr x 2 cols), gate update local to WG, per-dir device-scope barrier.
// LDS ~92.4KB -> exactly 1 WG/CU, grid==256==#CUs -> co-residency guaranteed.
// ---------------------------------------------------------------------------
DEVFN void gbar(int* cnt, int target) {
    __syncthreads();
    if (threadIdx.x == 0) {
        __threadfence();   // release: writeback local L2 (h-slice stores)
        __hip_atomic_fetch_add(cnt, 1, __ATOMIC_RELAXED, __HIP_MEMORY_SCOPE_AGENT);
        while (__hip_atomic_load(cnt, __ATOMIC_RELAXED, __HIP_MEMORY_SCOPE_AGENT) < target)
            __builtin_amdgcn_s_sleep(2);
    }
    __syncthreads();
}

__global__ __launch_bounds__(256)
void gru_step_all(const float* __restrict__ xpF, const float* __restrict__ xpB,
                  const float* __restrict__ rkF, const float* __restrict__ rkB,
                  const float* __restrict__ bF,  const float* __restrict__ bB,
                  float* __restrict__ ysF, float* __restrict__ ysB,
                  float* __restrict__ hfin,
                  const int* __restrict__ mask, int T, int barIdx) {
    __shared__ __align__(16) float h_lds[32][516];
    __shared__ __align__(16) float w_lds[12][516];
    __shared__ float inn_lds[32][12];
    __shared__ float bz[4], br[4], bh0s[4], bh1s[4];

    const int tid  = threadIdx.x;
    const int dir  = blockIdx.x & 1;
    const int u0   = (blockIdx.x >> 1) * 4;
    const float* xp = dir ? xpB : xpF;
    const float* rk = dir ? rkB : rkF;
    float*       ys = dir ? ysB : ysF;
    int* cnt = &g_bar[barIdx * 2 + dir];

    // persistent weight slice -> LDS (one-time)
#pragma unroll
    for (int c = 0; c < 12; ++c) {
        int g = c >> 2, j = c & 3;
        int col = g * 512 + u0 + j;
        for (int k = tid; k < 512; k += 256)
            w_lds[c][k] = rk[(size_t)k * G3 + col];
    }
    if (tid < 4) {
        const float* bw = dir ? bB : bF;
        int u = u0 + tid;
        bz[tid]   = bw[u]        + bw[G3 + u];
        br[tid]   = bw[512 + u]  + bw[G3 + 512 + u];
        bh0s[tid] = bw[1024 + u];
        bh1s[tid] = bw[G3 + 1024 + u];
    }

    const int gb = tid >> 2, gj = tid & 3;          // gate-phase coords (tid<128)
    const int db = tid / 6,  dc = tid - (tid / 6) * 6; // dot-phase coords (tid<192)

    for (int step = 0; step < T; ++step) {
        const int p  = step & 1;
        const int tt = dir ? (T - 1 - step) : step;

        // A: stage h into LDS (step 0: zeros)
        if (step == 0) {
            float4* hz = (float4*)&h_lds[0][0];
            for (int q = tid; q < (32 * 516) / 4; q += 256)
                hz[q] = make_float4(0.f, 0.f, 0.f, 0.f);
        } else {
            const float4* src = (const float4*)&g_Hbuf[p][dir][0][0];
            for (int q = tid; q < 4096; q += 256) {
                int b = q >> 7, k4 = q & 127;
                *(float4*)&h_lds[b][k4 << 2] = src[q];
            }
        }
        __syncthreads();

        // B: prefetch xproj row + mask (latency hides under dot phase)
        float xz = 0.f, xr = 0.f, xh = 0.f; int m = 0;
        if (tid < 128) {
            const float* xb = xp + ((size_t)gb * T + tt) * G3 + u0 + gj;
            xz = xb[0]; xr = xb[512]; xh = xb[1024];
            m = mask[gb * T + tt];
        }

        // C: dot products (192 threads x 2 cols x k=512)
        if (tid < 192) {
            const float* hb = h_lds[db];
            const float* w0 = w_lds[2 * dc];
            const float* w1 = w_lds[2 * dc + 1];
            float a0 = 0.f, a1 = 0.f;
#pragma unroll 8
            for (int k = 0; k < 512; k += 4) {
                float4 hv = *(const float4*)&hb[k];
                float4 wa = *(const float4*)&w0[k];
                float4 wb = *(const float4*)&w1[k];
                a0 += hv.x * wa.x + hv.y * wa.y + hv.z * wa.z + hv.w * wa.w;
                a1 += hv.x * wb.x + hv.y * wb.y + hv.z * wb.z + hv.w * wb.w;
            }
            inn_lds[db][2 * dc]     = a0;
            inn_lds[db][2 * dc + 1] = a1;
        }
        __syncthreads();

        // D: gate update + state/ys writes (128 threads: (b, j))
        if (tid < 128) {
            float hold = h_lds[gb][u0 + gj];
            float z  = fsig(xz + inn_lds[gb][gj]     + bz[gj]);
            float r  = fsig(xr + inn_lds[gb][4 + gj] + br[gj]);
            float hh = tanhf(xh + bh0s[gj] + r * (inn_lds[gb][8 + gj] + bh1s[gj]));
            float hn = m ? (z * hold + (1.0f - z) * hh) : hold;
            g_Hbuf[p ^ 1][dir][gb][u0 + gj] = hn;
            ys[((size_t)gb * T + tt) * (size_t)H + u0 + gj] = m ? hn : 0.0f;
        }

        // E: per-dir grid barrier (128 arrivals)
        gbar(cnt, (step + 1) * 128);
    }

    if (tid < 128)
        hfin[((size_t)dir * B + gb) * H + u0 + gj] = g_Hbuf[T & 1][dir][gb][u0 + gj];
}

// ---------------------------------------------------------------------------
__global__ __launch_bounds__(256)
void final_assemble(const float* __restrict__ YF, const float* __restrict__ YB,
                    const float* __restrict__ hf, float* __restrict__ out) {
    int i = blockIdx.x * 256 + threadIdx.x;
    int e = i * 4;
    const int OUT = B * 128 * 1024;
    if (e < OUT) {
        int b = e >> 17, t = (e >> 10) & 127, g = e & 1023;
        const float* src = (g < 512)
            ? &YF[((size_t)b * 128 + t) * 512 + g]
            : &YB[((size_t)b * 128 + t) * 512 + (g - 512)];
        *(float4*)(out + e) = *(const float4*)src;
    } else {
        int e2 = e - OUT;
        int b = e2 >> 10, g = e2 & 1023;
        const float* src = (g < 512) ? &hf[(size_t)b * 512 + g]
                                     : &hf[(size_t)(B + b) * 512 + (g - 512)];
        *(float4*)(out + e) = *(const float4*)src;
    }
}

// ---------------------------------------------------------------------------
extern "C" void kernel_launch(void* const* d_in, const int* in_sizes, int n_in,
                              void* d_out, int out_size, void* d_ws, size_t ws_size,
                              hipStream_t stream) {
    (void)d_ws; (void)ws_size;
    const float* inputs = (const float*)d_in[0];
    const float *k_[4][2], *r_[4][2], *bb_[4][2];
    int idx = 3;
    for (int l = 0; l < 4; ++l)
        for (int d = 0; d < 2; ++d) {
            k_[l][d]  = (const float*)d_in[idx++];
            r_[l][d]  = (const float*)d_in[idx++];
            bb_[l][d] = (const float*)d_in[idx++];
        }

    float* XPF  = nullptr; float* XPB = nullptr;
    float* YF   = nullptr; float* YB  = nullptr;
    float* HFIN = nullptr;
    int *MK1 = nullptr, *MK2 = nullptr, *MK3 = nullptr, *MK4 = nullptr;
    hipGetSymbolAddress((void**)&XPF,  HIP_SYMBOL(g_XPF));
    hipGetSymbolAddress((void**)&XPB,  HIP_SYMBOL(g_XPB));
    hipGetSymbolAddress((void**)&YF,   HIP_SYMBOL(g_YF));
    hipGetSymbolAddress((void**)&YB,   HIP_SYMBOL(g_YB));
    hipGetSymbolAddress((void**)&HFIN, HIP_SYMBOL(g_HFIN));
    hipGetSymbolAddress((void**)&MK1,  HIP_SYMBOL(g_MK1));
    hipGetSymbolAddress((void**)&MK2,  HIP_SYMBOL(g_MK2));
    hipGetSymbolAddress((void**)&MK3,  HIP_SYMBOL(g_MK3));
    hipGetSymbolAddress((void**)&MK4,  HIP_SYMBOL(g_MK4));

    init_misc<<<1, 64, 0, stream>>>();

    mask1_kernel<<<B * T1 / 4, 256, 0, stream>>>(inputs, MK1);
    mask_down<<<(B * (T1 / 2) + 255) / 256, 256, 0, stream>>>(MK1, MK2, B * (T1 / 2), T1 / 2);
    mask_down<<<(B * (T1 / 4) + 255) / 256, 256, 0, stream>>>(MK2, MK3, B * (T1 / 4), T1 / 4);
    mask_down<<<(B * (T1 / 8) + 255) / 256, 256, 0, stream>>>(MK3, MK4, B * (T1 / 8), T1 / 8);

    // ---- layer 1 (input features, K=240) ----
    gemm_xproj<0><<<dim3(12, B * T1 / 128), 256, 0, stream>>>(
        inputs, nullptr, nullptr, k_[0][0], XPF, B * T1, F0, 1);
    gemm_xproj<0><<<dim3(12, B * T1 / 128), 256, 0, stream>>>(
        inputs, nullptr, nullptr, k_[0][1], XPB, B * T1, F0, 1);
    gru_step_all<<<256, 256, 0, stream>>>(XPF, XPB, r_[0][0], r_[0][1],
                                          bb_[0][0], bb_[0][1],
                                          YF, YB, HFIN, MK1, T1, 0);

    // ---- layers 2..4 (pyramid input, K=2048) ----
    int T = T1 / 2;
    for (int l = 1; l < 4; ++l) {
        int M = B * T;
        const int* mk = (l == 1) ? MK2 : (l == 2) ? MK3 : MK4;
        gemm_xproj<1><<<dim3(12, M / 128), 256, 0, stream>>>(
            nullptr, YF, YB, k_[l][0], XPF, M, 2048, T);
        gemm_xproj<1><<<dim3(12, M / 128), 256, 0, stream>>>(
            nullptr, YF, YB, k_[l][1], XPB, M, 2048, T);
        gru_step_all<<<256, 256, 0, stream>>>(XPF, XPB, r_[l][0], r_[l][1],
                                              bb_[l][0], bb_[l][1],
                                              YF, YB, HFIN, mk, T, l);
        T >>= 1;
    }

    final_assemble<<<(out_size / 4 + 255) / 256, 256, 0, stream>>>(YF, YB, HFIN, (float*)d_out);
}

// Round 4
// 36890.289 us; speedup vs baseline: 1.6095x; 1.6095x over previous
//
#include <hip/hip_runtime.h>
#include <cstdint>
#include <cstddef>

#define DEVFN __device__ __forceinline__

static constexpr int B  = 32;
static constexpr int T1 = 1024;
static constexpr int F0 = 240;
static constexpr int H  = 512;
static constexpr int G3 = 3 * H;   // 1536

// ---- module-scope scratch (device .bss; avoids unknown ws_size) ----
__device__ float g_XPF[(size_t)B * T1 * G3];
__device__ float g_XPB[(size_t)B * T1 * G3];
__device__ float g_YF [(size_t)B * T1 * H];
__device__ float g_YB [(size_t)B * T1 * H];
__device__ float g_HFIN[2 * B * H];
__device__ int   g_MK1[B * T1];
__device__ int   g_MK2[B * (T1 / 2)];
__device__ int   g_MK3[B * (T1 / 4)];
__device__ int   g_MK4[B * (T1 / 8)];
// batched-recurrence state: [parity][dir][b][k] — accessed ONLY via agent-scope
// atomics (cache-bypass), so no XCD coherence maintenance is ever needed.
__device__ __align__(16) float g_Hbuf[2][2][B][H];
// grid barriers: one per (layer, dir), padded to separate cache lines
__device__ int g_bar[8][32];

DEVFN float fsig(float x)  { return 1.0f / (1.0f + expf(-x)); }

// ---------------------------------------------------------------------------
__global__ void init_misc() {
    ((int*)g_bar)[threadIdx.x] = 0;   // 256 ints
}

// ---------------------------------------------------------------------------
// mask for layer 1: one wave per (b,t) row; any nonzero among 240 feats
// ---------------------------------------------------------------------------
__global__ __launch_bounds__(256) void mask1_kernel(const float* __restrict__ x,
                                                    int* __restrict__ mask) {
    int wave = blockIdx.x * 4 + (threadIdx.x >> 6);
    int lane = threadIdx.x & 63;
    if (wave >= B * T1) return;
    const float* row = x + (size_t)wave * F0;
    int nz = 0;
    for (int f = lane; f < F0; f += 64) nz |= (row[f] != 0.0f);
    nz = __any(nz);
    if (lane == 0) mask[wave] = nz ? 1 : 0;
}

__global__ __launch_bounds__(256) void mask_down(const int* __restrict__ mp,
                                                 int* __restrict__ m, int n, int Tn) {
    int i = blockIdx.x * 256 + threadIdx.x;
    if (i >= n) return;
    int b = i / Tn, t = i - b * Tn;
    m[i] = mp[b * 2 * Tn + 2 * t] | mp[b * 2 * Tn + 2 * t + 1];
}

// ---------------------------------------------------------------------------
// xproj GEMM (unchanged, passing): C[M][1536] = A[M][K] @ W[K][1536]
// ---------------------------------------------------------------------------
template <int PYR>
__global__ __launch_bounds__(256)
void gemm_xproj(const float* __restrict__ A,
                const float* __restrict__ YFp, const float* __restrict__ YBp,
                const float* __restrict__ W, float* __restrict__ C,
                int M, int K, int Tn) {
    __shared__ float At[16][128];
    __shared__ float Bs[16][128];
    int tid = threadIdx.x;
    int n0 = blockIdx.x * 128;
    int m0 = blockIdx.y * 128;
    int tm = tid & 15, tn = tid >> 4;
    float acc[8][8] = {};

    for (int k0 = 0; k0 < K; k0 += 16) {
#pragma unroll
        for (int it = 0; it < 2; ++it) {
            int i = tid + it * 256;
            int m = i >> 2, kg = (i & 3) * 4;
            int gm = m0 + m, gk = k0 + kg;
            float4 v;
            if (PYR == 0) {
                v = *(const float4*)(A + (size_t)gm * K + gk);
            } else {
                int b = gm / Tn, t = gm - b * Tn;
                int s = 2 * t + (gk >> 10);
                int g = gk & 1023;
                const float* src = (g < 512)
                    ? (YFp + ((size_t)(b * 2 * Tn + s) * 512 + g))
                    : (YBp + ((size_t)(b * 2 * Tn + s) * 512 + (g - 512)));
                v = *(const float4*)src;
            }
            At[kg + 0][m] = v.x; At[kg + 1][m] = v.y;
            At[kg + 2][m] = v.z; At[kg + 3][m] = v.w;
        }
#pragma unroll
        for (int it = 0; it < 2; ++it) {
            int i = tid + it * 256;
            int kk = i >> 5, n4 = (i & 31) * 4;
            *(float4*)&Bs[kk][n4] =
                *(const float4*)(W + (size_t)(k0 + kk) * G3 + n0 + n4);
        }
        __syncthreads();
#pragma unroll
        for (int kk = 0; kk < 16; ++kk) {
            float a[8], bb[8];
            *(float4*)&a[0]  = *(float4*)&At[kk][tm * 8];
            *(float4*)&a[4]  = *(float4*)&At[kk][tm * 8 + 4];
            *(float4*)&bb[0] = *(float4*)&Bs[kk][tn * 8];
            *(float4*)&bb[4] = *(float4*)&Bs[kk][tn * 8 + 4];
#pragma unroll
            for (int i = 0; i < 8; ++i)
#pragma unroll
                for (int j = 0; j < 8; ++j) acc[i][j] += a[i] * bb[j];
        }
        __syncthreads();
    }
#pragma unroll
    for (int i = 0; i < 8; ++i) {
        size_t row = (size_t)(m0 + tm * 8 + i) * G3 + n0 + tn * 8;
        *(float4*)(C + row)     = *(float4*)&acc[i][0];
        *(float4*)(C + row + 4) = *(float4*)&acc[i][4];
    }
}

// ---------------------------------------------------------------------------
// Fence-free per-dir grid barrier. Correctness: __syncthreads drains each
// wave's vmcnt before s_barrier, so every WG's bypass (sc1) h-stores are at
// the device coherence point before any thread performs the arrival add.
// No threadfence => no buffer_wbl2/buffer_inv (the R3 25us/step killer).
// ---------------------------------------------------------------------------
DEVFN void gbar(int* cnt, int target) {
    __syncthreads();
    if (threadIdx.x == 0) {
        asm volatile("s_waitcnt vmcnt(0)" ::: "memory");
        __hip_atomic_fetch_add(cnt, 1, __ATOMIC_RELAXED, __HIP_MEMORY_SCOPE_AGENT);
        while (__hip_atomic_load(cnt, __ATOMIC_RELAXED, __HIP_MEMORY_SCOPE_AGENT) < target)
            __builtin_amdgcn_s_sleep(8);
    }
    __syncthreads();
}

// ---------------------------------------------------------------------------
// Batched GRU recurrence, persistent cooperative kernel.
// 256 WGs x 256 thr; WG owns 4 h-cols (12 gate cols) with its 24KB weight
// slice persistent in LDS. Per step: stage h (agent-atomic u64 loads ->
// LDS), 2x3 register-microtile dots over 4 k-slices, gates, bypass h store,
// per-dir barrier. LDS ~97KB -> 1 WG/CU -> all 256 WGs co-resident.
// ---------------------------------------------------------------------------
__global__ __launch_bounds__(256)
void gru_step_all(const float* __restrict__ xpF, const float* __restrict__ xpB,
                  const float* __restrict__ rkF, const float* __restrict__ rkB,
                  const float* __restrict__ bF,  const float* __restrict__ bB,
                  float* __restrict__ ysF, float* __restrict__ ysB,
                  float* __restrict__ hfin,
                  const int* __restrict__ mask, int T, int barIdx) {
    __shared__ __align__(16) float h_lds[32][516];
    __shared__ __align__(16) float w_lds[12][516];
    __shared__ float pinn[32][12][4];
    __shared__ float bz[4], br[4], bh0s[4], bh1s[4];

    const int tid = threadIdx.x;
    const int dir = blockIdx.x & 1;
    const int u0  = (blockIdx.x >> 1) * 4;
    const float* xp = dir ? xpB : xpF;
    const float* rk = dir ? rkB : rkF;
    float*       ys = dir ? ysB : ysF;
    int* cnt = &g_bar[barIdx * 2 + dir][0];

    // one-time: weight slice (12 cols x 512 rows) -> LDS
#pragma unroll
    for (int c = 0; c < 12; ++c) {
        int g = c >> 2, j = c & 3;
        int col = g * 512 + u0 + j;
        for (int k = tid; k < 512; k += 256)
            w_lds[c][k] = rk[(size_t)k * G3 + col];
    }
    if (tid < 4) {
        const float* bw = dir ? bB : bF;
        int u = u0 + tid;
        bz[tid]   = bw[u]        + bw[G3 + u];
        br[tid]   = bw[512 + u]  + bw[G3 + 512 + u];
        bh0s[tid] = bw[1024 + u];
        bh1s[tid] = bw[G3 + 1024 + u];
    }

    // dot-phase coords: ks-major lane order => h reads are 4-way-broadcast,
    // 32 distinct rows per instr => bank-conflict-free (row stride 516 = 4*129)
    const int ks = tid >> 6;          // 0..3  k-slice of 128
    const int bp = (tid & 63) >> 2;   // 0..15 batch-pair
    const int ct = tid & 3;           // 0..3  col-triple
    // gate-phase coords (tid < 128)
    const int gb = tid >> 2, gj = tid & 3;

    for (int step = 0; step < T; ++step) {
        const int p  = step & 1;
        const int tt = dir ? (T - 1 - step) : step;

        // A: stage h into LDS (step 0: zeros; else bypass loads from IF)
        if (step == 0) {
            float4* hz = (float4*)&h_lds[0][0];
            for (int q = tid; q < (32 * 516) / 4; q += 256)
                hz[q] = make_float4(0.f, 0.f, 0.f, 0.f);
        } else {
            const unsigned long long* src =
                (const unsigned long long*)&g_Hbuf[p][dir][0][0];
#pragma unroll 16
            for (int i = tid; i < (32 * 512) / 2; i += 256) {
                unsigned long long v = __hip_atomic_load(
                    src + i, __ATOMIC_RELAXED, __HIP_MEMORY_SCOPE_AGENT);
                int fl = i << 1;
                *(unsigned long long*)&h_lds[fl >> 9][fl & 511] = v;
            }
        }
        __syncthreads();

        // B: prefetch xproj row + mask (hides under dot phase)
        float xz = 0.f, xr = 0.f, xh = 0.f; int m = 0;
        if (tid < 128) {
            const float* xb = xp + ((size_t)gb * T + tt) * G3 + u0 + gj;
            xz = xb[0]; xr = xb[512]; xh = xb[1024];
            m = mask[gb * T + tt];
        }

        // C: dots — 2 batches x 3 cols x 128 k per thread
        {
            const int b0 = bp << 1, c0 = ct * 3, kb = ks << 7;
            const float* h0 = &h_lds[b0][kb];
            const float* h1 = &h_lds[b0 + 1][kb];
            const float* wa = &w_lds[c0][kb];
            const float* wb = &w_lds[c0 + 1][kb];
            const float* wc = &w_lds[c0 + 2][kb];
            float a00 = 0.f, a01 = 0.f, a02 = 0.f;
            float a10 = 0.f, a11 = 0.f, a12 = 0.f;
#pragma unroll 8
            for (int kk = 0; kk < 128; kk += 4) {
                float4 x0 = *(const float4*)&h0[kk];
                float4 x1 = *(const float4*)&h1[kk];
                float4 va = *(const float4*)&wa[kk];
                float4 vb = *(const float4*)&wb[kk];
                float4 vc = *(const float4*)&wc[kk];
                a00 += x0.x*va.x + x0.y*va.y + x0.z*va.z + x0.w*va.w;
                a01 += x0.x*vb.x + x0.y*vb.y + x0.z*vb.z + x0.w*vb.w;
                a02 += x0.x*vc.x + x0.y*vc.y + x0.z*vc.z + x0.w*vc.w;
                a10 += x1.x*va.x + x1.y*va.y + x1.z*va.z + x1.w*va.w;
                a11 += x1.x*vb.x + x1.y*vb.y + x1.z*vb.z + x1.w*vb.w;
                a12 += x1.x*vc.x + x1.y*vc.y + x1.z*vc.z + x1.w*vc.w;
            }
            pinn[b0][c0][ks]     = a00;
            pinn[b0][c0 + 1][ks] = a01;
            pinn[b0][c0 + 2][ks] = a02;
            pinn[b0 + 1][c0][ks]     = a10;
            pinn[b0 + 1][c0 + 1][ks] = a11;
            pinn[b0 + 1][c0 + 2][ks] = a12;
        }
        __syncthreads();

        // D: gates (tid<128: thread = (batch gb, col gj))
        if (tid < 128) {
            float iz = pinn[gb][gj][0] + pinn[gb][gj][1]
                     + pinn[gb][gj][2] + pinn[gb][gj][3];
            float ir = pinn[gb][4 + gj][0] + pinn[gb][4 + gj][1]
                     + pinn[gb][4 + gj][2] + pinn[gb][4 + gj][3];
            float ih = pinn[gb][8 + gj][0] + pinn[gb][8 + gj][1]
                     + pinn[gb][8 + gj][2] + pinn[gb][8 + gj][3];
            float hold = h_lds[gb][u0 + gj];
            float z  = fsig(xz + iz + bz[gj]);
            float r  = fsig(xr + ir + br[gj]);
            float hh = tanhf(xh + bh0s[gj] + r * (ih + bh1s[gj]));
            float hn = m ? (z * hold + (1.0f - z) * hh) : hold;
            __hip_atomic_store(&g_Hbuf[p ^ 1][dir][gb][u0 + gj], hn,
                               __ATOMIC_RELAXED, __HIP_MEMORY_SCOPE_AGENT);
            ys[((size_t)gb * T + tt) * (size_t)H + u0 + gj] = m ? hn : 0.0f;
            if (step == T - 1)
                hfin[((size_t)dir * B + gb) * H + u0 + gj] = hn;
        }

        // E: per-dir grid barrier (128 arrivals/step)
        gbar(cnt, (step + 1) * 128);
    }
}

// ---------------------------------------------------------------------------
__global__ __launch_bounds__(256)
void final_assemble(const float* __restrict__ YF, const float* __restrict__ YB,
                    const float* __restrict__ hf, float* __restrict__ out) {
    int i = blockIdx.x * 256 + threadIdx.x;
    int e = i * 4;
    const int OUT = B * 128 * 1024;
    if (e < OUT) {
        int b = e >> 17, t = (e >> 10) & 127, g = e & 1023;
        const float* src = (g < 512)
            ? &YF[((size_t)b * 128 + t) * 512 + g]
            : &YB[((size_t)b * 128 + t) * 512 + (g - 512)];
        *(float4*)(out + e) = *(const float4*)src;
    } else {
        int e2 = e - OUT;
        int b = e2 >> 10, g = e2 & 1023;
        const float* src = (g < 512) ? &hf[(size_t)b * 512 + g]
                                     : &hf[(size_t)(B + b) * 512 + (g - 512)];
        *(float4*)(out + e) = *(const float4*)src;
    }
}

// ---------------------------------------------------------------------------
extern "C" void kernel_launch(void* const* d_in, const int* in_sizes, int n_in,
                              void* d_out, int out_size, void* d_ws, size_t ws_size,
                              hipStream_t stream) {
    (void)d_ws; (void)ws_size;
    const float* inputs = (const float*)d_in[0];
    const float *k_[4][2], *r_[4][2], *bb_[4][2];
    int idx = 3;
    for (int l = 0; l < 4; ++l)
        for (int d = 0; d < 2; ++d) {
            k_[l][d]  = (const float*)d_in[idx++];
            r_[l][d]  = (const float*)d_in[idx++];
            bb_[l][d] = (const float*)d_in[idx++];
        }

    float* XPF  = nullptr; float* XPB = nullptr;
    float* YF   = nullptr; float* YB  = nullptr;
    float* HFIN = nullptr;
    int *MK1 = nullptr, *MK2 = nullptr, *MK3 = nullptr, *MK4 = nullptr;
    hipGetSymbolAddress((void**)&XPF,  HIP_SYMBOL(g_XPF));
    hipGetSymbolAddress((void**)&XPB,  HIP_SYMBOL(g_XPB));
    hipGetSymbolAddress((void**)&YF,   HIP_SYMBOL(g_YF));
    hipGetSymbolAddress((void**)&YB,   HIP_SYMBOL(g_YB));
    hipGetSymbolAddress((void**)&HFIN, HIP_SYMBOL(g_HFIN));
    hipGetSymbolAddress((void**)&MK1,  HIP_SYMBOL(g_MK1));
    hipGetSymbolAddress((void**)&MK2,  HIP_SYMBOL(g_MK2));
    hipGetSymbolAddress((void**)&MK3,  HIP_SYMBOL(g_MK3));
    hipGetSymbolAddress((void**)&MK4,  HIP_SYMBOL(g_MK4));

    init_misc<<<1, 256, 0, stream>>>();

    mask1_kernel<<<B * T1 / 4, 256, 0, stream>>>(inputs, MK1);
    mask_down<<<(B * (T1 / 2) + 255) / 256, 256, 0, stream>>>(MK1, MK2, B * (T1 / 2), T1 / 2);
    mask_down<<<(B * (T1 / 4) + 255) / 256, 256, 0, stream>>>(MK2, MK3, B * (T1 / 4), T1 / 4);
    mask_down<<<(B * (T1 / 8) + 255) / 256, 256, 0, stream>>>(MK3, MK4, B * (T1 / 8), T1 / 8);

    // ---- layer 1 (input features, K=240) ----
    gemm_xproj<0><<<dim3(12, B * T1 / 128), 256, 0, stream>>>(
        inputs, nullptr, nullptr, k_[0][0], XPF, B * T1, F0, 1);
    gemm_xproj<0><<<dim3(12, B * T1 / 128), 256, 0, stream>>>(
        inputs, nullptr, nullptr, k_[0][1], XPB, B * T1, F0, 1);
    gru_step_all<<<256, 256, 0, stream>>>(XPF, XPB, r_[0][0], r_[0][1],
                                          bb_[0][0], bb_[0][1],
                                          YF, YB, HFIN, MK1, T1, 0);

    // ---- layers 2..4 (pyramid input, K=2048) ----
    int T = T1 / 2;
    for (int l = 1; l < 4; ++l) {
        int M = B * T;
        const int* mk = (l == 1) ? MK2 : (l == 2) ? MK3 : MK4;
        gemm_xproj<1><<<dim3(12, M / 128), 256, 0, stream>>>(
            nullptr, YF, YB, k_[l][0], XPF, M, 2048, T);
        gemm_xproj<1><<<dim3(12, M / 128), 256, 0, stream>>>(
            nullptr, YF, YB, k_[l][1], XPB, M, 2048, T);
        gru_step_all<<<256, 256, 0, stream>>>(XPF, XPB, r_[l][0], r_[l][1],
                                              bb_[l][0], bb_[l][1],
                                              YF, YB, HFIN, mk, T, l);
        T >>= 1;
    }

    final_assemble<<<(out_size / 4 + 255) / 256, 256, 0, stream>>>(YF, YB, HFIN, (float*)d_out);
}

// Round 8
// 21974.980 us; speedup vs baseline: 2.7020x; 1.6787x over previous
//
#include <hip/hip_runtime.h>
#include <cstdint>
#include <cstddef>

#define DEVFN __device__ __forceinline__

static constexpr int B  = 32;
static constexpr int T1 = 1024;
static constexpr int F0 = 240;
static constexpr int H  = 512;
static constexpr int G3 = 3 * H;   // 1536

// ---- module-scope scratch (device .bss; avoids unknown ws_size) ----
__device__ float g_XPF[(size_t)B * T1 * G3];
__device__ float g_XPB[(size_t)B * T1 * G3];
__device__ float g_YF [(size_t)B * T1 * H];
__device__ float g_YB [(size_t)B * T1 * H];
__device__ float g_HFIN[2 * B * H];
__device__ int   g_MK1[B * T1];
__device__ int   g_MK2[B * (T1 / 2)];
__device__ int   g_MK3[B * (T1 / 4)];
__device__ int   g_MK4[B * (T1 / 8)];
// batched-recurrence state: [parity][dir][b][k] — accessed ONLY via agent-scope
// atomics (cache-bypass), so no XCD coherence maintenance is ever needed.
__device__ __align__(16) float g_Hbuf[2][2][B][H];
// grid barriers: one per (layer, dir), padded to separate cache lines
__device__ int g_bar[8][32];

DEVFN float fsig(float x)  { return 1.0f / (1.0f + expf(-x)); }
// XOR-swizzled word index into the 32x512 h tile (flips bank bits 2..4)
DEVFN int hsw(int b, int k) { return b * 512 + (k ^ ((b & 7) << 2)); }

// bf16 round-to-nearest-even helpers for the split-bf16 GEMM
DEVFN unsigned short f2bf(float f) {
    unsigned u = __float_as_uint(f);
    return (unsigned short)((u + 0x7FFFu + ((u >> 16) & 1u)) >> 16);
}
DEVFN float bf2f(unsigned short h) { return __uint_as_float(((unsigned)h) << 16); }

typedef __attribute__((ext_vector_type(8))) short bf16x8;
typedef __attribute__((ext_vector_type(4))) float f32x4;

// ---------------------------------------------------------------------------
__global__ void init_misc() {
    ((int*)g_bar)[threadIdx.x] = 0;   // 256 ints
}

// ---------------------------------------------------------------------------
__global__ __launch_bounds__(256) void mask1_kernel(const float* __restrict__ x,
                                                    int* __restrict__ mask) {
    int wave = blockIdx.x * 4 + (threadIdx.x >> 6);
    int lane = threadIdx.x & 63;
    if (wave >= B * T1) return;
    const float* row = x + (size_t)wave * F0;
    int nz = 0;
    for (int f = lane; f < F0; f += 64) nz |= (row[f] != 0.0f);
    nz = __any(nz);
    if (lane == 0) mask[wave] = nz ? 1 : 0;
}

__global__ __launch_bounds__(256) void mask_down(const int* __restrict__ mp,
                                                 int* __restrict__ m, int n, int Tn) {
    int i = blockIdx.x * 256 + threadIdx.x;
    if (i >= n) return;
    int b = i / Tn, t = i - b * Tn;
    m[i] = mp[b * 2 * Tn + 2 * t] | mp[b * 2 * Tn + 2 * t + 1];
}

// ---------------------------------------------------------------------------
// Split-bf16 MFMA xproj GEMM: C[M][1536] = A[M][K] @ W[K][1536], fp32 in/out.
// a = a_hi + a_lo (bf16 each); a.w ~= ah.wh + ah.wl + al.wh (drop al.wl ~2^-18)
// => ~fp32 accuracy at bf16 MFMA rate / 3.
// Tile 128x128, BK=32, 256 thr = 4 waves (2x2), wave = 4x4 frags of
// mfma_f32_16x16x32_bf16. A staged k-contiguous [128][40] (pad->2-way-free);
// W transpose-staged [128][40] so B-frags are contiguous 16B (m92 pattern).
// C/D: col=lane&15, row=(lane>>4)*4+reg (m89/m91).
// PYR=1: A row m=(b*Tn+t), col f in [0,2048) = pyramid concat of YFp/YBp.
// ---------------------------------------------------------------------------
template <int PYR>
__global__ __launch_bounds__(256)
void gemm_xproj_mfma(const float* __restrict__ A,
                     const float* __restrict__ YFp, const float* __restrict__ YBp,
                     const float* __restrict__ W, float* __restrict__ C,
                     int M, int K, int Tn) {
    __shared__ __align__(16) unsigned short At_h[128][40];
    __shared__ __align__(16) unsigned short At_l[128][40];
    __shared__ __align__(16) unsigned short Wt_h[128][40];
    __shared__ __align__(16) unsigned short Wt_l[128][40];

    const int tid  = threadIdx.x;
    const int n0   = blockIdx.x * 128;
    const int m0   = blockIdx.y * 128;
    const int lane = tid & 63;
    const int wv   = tid >> 6;
    const int wm   = (wv >> 1) * 64;     // wave tile origin in M
    const int wn   = (wv & 1) * 64;      // wave tile origin in N
    const int fr   = lane & 15;          // fragment row/col selector
    const int ko   = (lane >> 4) * 8;    // k-octet

    f32x4 acc[4][4] = {};

    for (int k0 = 0; k0 < K; k0 += 32) {
        // ---- stage A (hi/lo), k-contiguous ----
#pragma unroll
        for (int it = 0; it < 4; ++it) {
            int i = tid + it * 256;              // 0..1023 float4s
            int m = i >> 3, kq = (i & 7) * 4;
            int gm = m0 + m, gk = k0 + kq;
            float4 v = make_float4(0.f, 0.f, 0.f, 0.f);
            if (PYR == 0) {
                if (gk < K) v = *(const float4*)(A + (size_t)gm * K + gk);
            } else {
                int b = gm / Tn, t = gm - b * Tn;
                int s = 2 * t + (gk >> 10);
                int g = gk & 1023;
                const float* src = (g < 512)
                    ? (YFp + ((size_t)(b * 2 * Tn + s) * 512 + g))
                    : (YBp + ((size_t)(b * 2 * Tn + s) * 512 + (g - 512)));
                v = *(const float4*)src;
            }
            ushort4 hh, ll;
            hh.x = f2bf(v.x); ll.x = f2bf(v.x - bf2f(hh.x));
            hh.y = f2bf(v.y); ll.y = f2bf(v.y - bf2f(hh.y));
            hh.z = f2bf(v.z); ll.z = f2bf(v.z - bf2f(hh.z));
            hh.w = f2bf(v.w); ll.w = f2bf(v.w - bf2f(hh.w));
            *(ushort4*)&At_h[m][kq] = hh;
            *(ushort4*)&At_l[m][kq] = ll;
        }
        // ---- stage W (hi/lo), transposed to [n][k] ----
#pragma unroll
        for (int it = 0; it < 4; ++it) {
            int i = tid + it * 256;              // 0..1023 float4s
            int kk = i >> 5, c = (i & 31) * 4;
            float4 v = make_float4(0.f, 0.f, 0.f, 0.f);
            if (k0 + kk < K)
                v = *(const float4*)(W + (size_t)(k0 + kk) * G3 + n0 + c);
            unsigned short h;
            h = f2bf(v.x); Wt_h[c + 0][kk] = h; Wt_l[c + 0][kk] = f2bf(v.x - bf2f(h));
            h = f2bf(v.y); Wt_h[c + 1][kk] = h; Wt_l[c + 1][kk] = f2bf(v.y - bf2f(h));
            h = f2bf(v.z); Wt_h[c + 2][kk] = h; Wt_l[c + 2][kk] = f2bf(v.z - bf2f(h));
            h = f2bf(v.w); Wt_h[c + 3][kk] = h; Wt_l[c + 3][kk] = f2bf(v.w - bf2f(h));
        }
        __syncthreads();

        bf16x8 ah[4], al[4], bh[4], bl[4];
#pragma unroll
        for (int f = 0; f < 4; ++f) {
            ah[f] = *(const bf16x8*)&At_h[wm + f * 16 + fr][ko];
            al[f] = *(const bf16x8*)&At_l[wm + f * 16 + fr][ko];
            bh[f] = *(const bf16x8*)&Wt_h[wn + f * 16 + fr][ko];
            bl[f] = *(const bf16x8*)&Wt_l[wn + f * 16 + fr][ko];
        }
#pragma unroll
        for (int i = 0; i < 4; ++i)
#pragma unroll
            for (int j = 0; j < 4; ++j) {
                acc[i][j] = __builtin_amdgcn_mfma_f32_16x16x32_bf16(ah[i], bh[j], acc[i][j], 0, 0, 0);
                acc[i][j] = __builtin_amdgcn_mfma_f32_16x16x32_bf16(ah[i], bl[j], acc[i][j], 0, 0, 0);
                acc[i][j] = __builtin_amdgcn_mfma_f32_16x16x32_bf16(al[i], bh[j], acc[i][j], 0, 0, 0);
            }
        __syncthreads();
    }

    const int orow = (lane >> 4) * 4;
#pragma unroll
    for (int i = 0; i < 4; ++i)
#pragma unroll
        for (int j = 0; j < 4; ++j)
#pragma unroll
            for (int q = 0; q < 4; ++q) {
                int row = m0 + wm + i * 16 + orow + q;
                int col = n0 + wn + j * 16 + fr;
                C[(size_t)row * G3 + col] = acc[i][j][q];
            }
}

// ---------------------------------------------------------------------------
// Fence-free per-dir grid barrier (proven R4). __syncthreads drains vmcnt in
// every wave before s_barrier => all bypass h-stores are at the coherence
// point before the arrival add. No buffer_wbl2/inv anywhere.
// ---------------------------------------------------------------------------
DEVFN void gbar(int* cnt, int target) {
    __syncthreads();
    if (threadIdx.x == 0) {
        asm volatile("s_waitcnt vmcnt(0)" ::: "memory");
        __hip_atomic_fetch_add(cnt, 1, __ATOMIC_RELAXED, __HIP_MEMORY_SCOPE_AGENT);
        while (__hip_atomic_load(cnt, __ATOMIC_RELAXED, __HIP_MEMORY_SCOPE_AGENT) < target)
            __builtin_amdgcn_s_sleep(4);
    }
    __syncthreads();
}

// ---------------------------------------------------------------------------
// Batched GRU recurrence, persistent cooperative kernel (v3, unchanged from
// R5/R6 — still unmeasured due to infra). 256 WGs x 512 thr; weights in
// registers; XOR-swizzled h tile; ks-swizzled partials.
// ---------------------------------------------------------------------------
__global__ __launch_bounds__(512, 2)
void gru_step_all(const float* __restrict__ xpF, const float* __restrict__ xpB,
                  const float* __restrict__ rkF, const float* __restrict__ rkB,
                  const float* __restrict__ bF,  const float* __restrict__ bB,
                  float* __restrict__ ysF, float* __restrict__ ysB,
                  float* __restrict__ hfin,
                  const int* __restrict__ mask, int T, int barIdx) {
    __shared__ __align__(16) float h_flat[32 * 512];
    __shared__ __align__(16) float pinn[32][12][32];
    __shared__ float bz[4], br[4], bh0s[4], bh1s[4];

    const int tid = threadIdx.x;
    const int dir = blockIdx.x & 1;
    const int u0  = (blockIdx.x >> 1) * 4;
    const float* xp = dir ? xpB : xpF;
    const float* rk = dir ? rkB : rkF;
    float*       ys = dir ? ysB : ysF;
    int* cnt = &g_bar[barIdx * 2 + dir][0];

    // dot-phase thread coords: tid = ks*16 + bp*2 + ct2
    const int ks  = tid >> 4;         // 0..31, k-slice of 16
    const int bp  = (tid >> 1) & 7;   // 0..7, batch group (b = bp + 8i)
    const int ct2 = tid & 1;          // 0..1, col-sextet
    const int kbase = ks * 16;
    const int cbase = ct2 * 6;
    // gate-phase coords (tid < 128)
    const int gb = tid >> 2, gj = tid & 3;

    // one-time: weight slice -> registers (static indices only)
    float w_reg[6][16];
#pragma unroll
    for (int c = 0; c < 6; ++c) {
        int cc  = cbase + c;
        int col = (cc >> 2) * 512 + u0 + (cc & 3);
#pragma unroll
        for (int i = 0; i < 16; ++i)
            w_reg[c][i] = rk[(size_t)(kbase + i) * G3 + col];
    }
    if (tid < 4) {
        const float* bw = dir ? bB : bF;
        int u = u0 + tid;
        bz[tid]   = bw[u]        + bw[G3 + u];
        br[tid]   = bw[512 + u]  + bw[G3 + 512 + u];
        bh0s[tid] = bw[1024 + u];
        bh1s[tid] = bw[G3 + 1024 + u];
    }

    for (int step = 0; step < T; ++step) {
        const int p  = step & 1;
        const int tt = dir ? (T - 1 - step) : step;

        // A: stage h into LDS (step 0: zeros; else bypass loads from IF)
        if (step == 0) {
            for (int q = tid; q < (32 * 512) / 4; q += 512)
                ((float4*)h_flat)[q] = make_float4(0.f, 0.f, 0.f, 0.f);
        } else {
            const unsigned long long* src =
                (const unsigned long long*)&g_Hbuf[p][dir][0][0];
#pragma unroll 16
            for (int i = tid; i < 8192; i += 512) {
                unsigned long long v = __hip_atomic_load(
                    src + i, __ATOMIC_RELAXED, __HIP_MEMORY_SCOPE_AGENT);
                int e = i << 1;                  // word index
                *(unsigned long long*)&h_flat[hsw(e >> 9, e & 511)] = v;
            }
        }
        __syncthreads();

        // B: prefetch xproj row + mask (hides under dot phase)
        float xz = 0.f, xr = 0.f, xh = 0.f; int m = 0;
        if (tid < 128) {
            const float* xb = xp + ((size_t)gb * T + tt) * G3 + u0 + gj;
            xz = xb[0]; xr = xb[512]; xh = xb[1024];
            m = mask[gb * T + tt];
        }

        // C: dots — 4 batches x 6 cols x 16 k per thread, w in registers
        {
            float acc[4][6];
#pragma unroll
            for (int i = 0; i < 4; ++i)
#pragma unroll
                for (int c = 0; c < 6; ++c) acc[i][c] = 0.f;
#pragma unroll
            for (int kk4 = 0; kk4 < 4; ++kk4) {
                float4 hq[4];
#pragma unroll
                for (int i = 0; i < 4; ++i) {
                    int b = bp + 8 * i;
                    hq[i] = *(const float4*)&h_flat[hsw(b, kbase + kk4 * 4)];
                }
#pragma unroll
                for (int i = 0; i < 4; ++i)
#pragma unroll
                    for (int c = 0; c < 6; ++c)
                        acc[i][c] += hq[i].x * w_reg[c][kk4 * 4 + 0]
                                   + hq[i].y * w_reg[c][kk4 * 4 + 1]
                                   + hq[i].z * w_reg[c][kk4 * 4 + 2]
                                   + hq[i].w * w_reg[c][kk4 * 4 + 3];
            }
#pragma unroll
            for (int i = 0; i < 4; ++i) {
                int b = bp + 8 * i;
                int ko2 = ks ^ ((b & 7) << 2);
#pragma unroll
                for (int c = 0; c < 6; ++c)
                    pinn[b][cbase + c][ko2] = acc[i][c];
            }
        }
        __syncthreads();

        // D: gates (tid<128: thread = (batch gb, col gj)), float4 reduce
        if (tid < 128) {
            float iz = 0.f, ir = 0.f, ih = 0.f;
            int sw = (gb & 7) << 2;
#pragma unroll
            for (int q = 0; q < 8; ++q) {
                int o = (q * 4) ^ sw;
                float4 vz = *(const float4*)&pinn[gb][gj][o];
                float4 vr = *(const float4*)&pinn[gb][4 + gj][o];
                float4 vh = *(const float4*)&pinn[gb][8 + gj][o];
                iz += vz.x + vz.y + vz.z + vz.w;
                ir += vr.x + vr.y + vr.z + vr.w;
                ih += vh.x + vh.y + vh.z + vh.w;
            }
            float hold = h_flat[hsw(gb, u0 + gj)];
            float z  = fsig(xz + iz + bz[gj]);
            float r  = fsig(xr + ir + br[gj]);
            float hh = tanhf(xh + bh0s[gj] + r * (ih + bh1s[gj]));
            float hn = m ? (z * hold + (1.0f - z) * hh) : hold;
            __hip_atomic_store(&g_Hbuf[p ^ 1][dir][gb][u0 + gj], hn,
                               __ATOMIC_RELAXED, __HIP_MEMORY_SCOPE_AGENT);
            ys[((size_t)gb * T + tt) * (size_t)H + u0 + gj] = m ? hn : 0.0f;
            if (step == T - 1)
                hfin[((size_t)dir * B + gb) * H + u0 + gj] = hn;
        }

        // E: per-dir grid barrier (128 arrivals/step)
        gbar(cnt, (step + 1) * 128);
    }
}

// ---------------------------------------------------------------------------
__global__ __launch_bounds__(256)
void final_assemble(const float* __restrict__ YF, const float* __restrict__ YB,
                    const float* __restrict__ hf, float* __restrict__ out) {
    int i = blockIdx.x * 256 + threadIdx.x;
    int e = i * 4;
    const int OUT = B * 128 * 1024;
    if (e < OUT) {
        int b = e >> 17, t = (e >> 10) & 127, g = e & 1023;
        const float* src = (g < 512)
            ? &YF[((size_t)b * 128 + t) * 512 + g]
            : &YB[((size_t)b * 128 + t) * 512 + (g - 512)];
        *(float4*)(out + e) = *(const float4*)src;
    } else {
        int e2 = e - OUT;
        int b = e2 >> 10, g = e2 & 1023;
        const float* src = (g < 512) ? &hf[(size_t)b * 512 + g]
                                     : &hf[(size_t)(B + b) * 512 + (g - 512)];
        *(float4*)(out + e) = *(const float4*)src;
    }
}

// ---------------------------------------------------------------------------
extern "C" void kernel_launch(void* const* d_in, const int* in_sizes, int n_in,
                              void* d_out, int out_size, void* d_ws, size_t ws_size,
                              hipStream_t stream) {
    (void)d_ws; (void)ws_size;
    const float* inputs = (const float*)d_in[0];
    const float *k_[4][2], *r_[4][2], *bb_[4][2];
    int idx = 3;
    for (int l = 0; l < 4; ++l)
        for (int d = 0; d < 2; ++d) {
            k_[l][d]  = (const float*)d_in[idx++];
            r_[l][d]  = (const float*)d_in[idx++];
            bb_[l][d] = (const float*)d_in[idx++];
        }

    float* XPF  = nullptr; float* XPB = nullptr;
    float* YF   = nullptr; float* YB  = nullptr;
    float* HFIN = nullptr;
    int *MK1 = nullptr, *MK2 = nullptr, *MK3 = nullptr, *MK4 = nullptr;
    hipGetSymbolAddress((void**)&XPF,  HIP_SYMBOL(g_XPF));
    hipGetSymbolAddress((void**)&XPB,  HIP_SYMBOL(g_XPB));
    hipGetSymbolAddress((void**)&YF,   HIP_SYMBOL(g_YF));
    hipGetSymbolAddress((void**)&YB,   HIP_SYMBOL(g_YB));
    hipGetSymbolAddress((void**)&HFIN, HIP_SYMBOL(g_HFIN));
    hipGetSymbolAddress((void**)&MK1,  HIP_SYMBOL(g_MK1));
    hipGetSymbolAddress((void**)&MK2,  HIP_SYMBOL(g_MK2));
    hipGetSymbolAddress((void**)&MK3,  HIP_SYMBOL(g_MK3));
    hipGetSymbolAddress((void**)&MK4,  HIP_SYMBOL(g_MK4));

    init_misc<<<1, 256, 0, stream>>>();

    mask1_kernel<<<B * T1 / 4, 256, 0, stream>>>(inputs, MK1);
    mask_down<<<(B * (T1 / 2) + 255) / 256, 256, 0, stream>>>(MK1, MK2, B * (T1 / 2), T1 / 2);
    mask_down<<<(B * (T1 / 4) + 255) / 256, 256, 0, stream>>>(MK2, MK3, B * (T1 / 4), T1 / 4);
    mask_down<<<(B * (T1 / 8) + 255) / 256, 256, 0, stream>>>(MK3, MK4, B * (T1 / 8), T1 / 8);

    // ---- layer 1 (input features, K=240) ----
    gemm_xproj_mfma<0><<<dim3(12, B * T1 / 128), 256, 0, stream>>>(
        inputs, nullptr, nullptr, k_[0][0], XPF, B * T1, F0, 1);
    gemm_xproj_mfma<0><<<dim3(12, B * T1 / 128), 256, 0, stream>>>(
        inputs, nullptr, nullptr, k_[0][1], XPB, B * T1, F0, 1);
    gru_step_all<<<256, 512, 0, stream>>>(XPF, XPB, r_[0][0], r_[0][1],
                                          bb_[0][0], bb_[0][1],
                                          YF, YB, HFIN, MK1, T1, 0);

    // ---- layers 2..4 (pyramid input, K=2048) ----
    int T = T1 / 2;
    for (int l = 1; l < 4; ++l) {
        int M = B * T;
        const int* mk = (l == 1) ? MK2 : (l == 2) ? MK3 : MK4;
        gemm_xproj_mfma<1><<<dim3(12, M / 128), 256, 0, stream>>>(
            nullptr, YF, YB, k_[l][0], XPF, M, 2048, T);
        gemm_xproj_mfma<1><<<dim3(12, M / 128), 256, 0, stream>>>(
            nullptr, YF, YB, k_[l][1], XPB, M, 2048, T);
        gru_step_all<<<256, 512, 0, stream>>>(XPF, XPB, r_[l][0], r_[l][1],
                                              bb_[l][0], bb_[l][1],
                                              YF, YB, HFIN, mk, T, l);
        T >>= 1;
    }

    final_assemble<<<(out_size / 4 + 255) / 256, 256, 0, stream>>>(YF, YB, HFIN, (float*)d_out);
}